// Round 1
// baseline (290.350 us; speedup 1.0000x reference)
//
#include <hip/hip_runtime.h>
#include <hip/hip_bf16.h>

// Sizes fixed by the reference: IN=128, HD=128, T=8, H=8, D=16.
// Output depends ONLY on: emb = segment_sum(typed_linear(x[src], W_w, etype), dst)
// out = elu(emb + x @ W_res + b_res).  Attention path is dead code.
//
// Pipeline:
//   CSR(dst) -> per-node type-aggregation agg[N, 8*128 (+128 x-residual)] bf16
//   -> single MFMA GEMM [padM,1152]x[1152,128] with bias+ELU epilogue.

#define KTOT 1152   // 8*128 (typed agg) + 128 (x residual)

typedef __bf16 bf16x8 __attribute__((ext_vector_type(8)));
typedef float f32x4 __attribute__((ext_vector_type(4)));

__device__ __forceinline__ void gload_lds16(const void* g, void* l) {
  __builtin_amdgcn_global_load_lds(
      (const __attribute__((address_space(1))) unsigned int*)g,
      (__attribute__((address_space(3))) unsigned int*)l, 16, 0, 0);
}

// ---------------- CSR build ----------------
__global__ void k_hist(const int* __restrict__ dst, int* __restrict__ deg, int E) {
  int e = blockIdx.x * 256 + threadIdx.x;
  if (e < E) atomicAdd(&deg[dst[e]], 1);
}

// inclusive Hillis-Steele per 256-block; writes exclusive prefix + block sum
__global__ void k_scan(const int* __restrict__ in, int* __restrict__ out_ex,
                       int* __restrict__ bsum, int N) {
  __shared__ int s[256];
  int tid = threadIdx.x;
  int i = blockIdx.x * 256 + tid;
  int v = (i < N) ? in[i] : 0;
  s[tid] = v;
  __syncthreads();
  for (int off = 1; off < 256; off <<= 1) {
    int t = (tid >= off) ? s[tid - off] : 0;
    __syncthreads();
    if (tid >= off) s[tid] += t;
    __syncthreads();
  }
  if (i < N) out_ex[i] = s[tid] - v;
  if (bsum != nullptr && tid == 255) bsum[blockIdx.x] = s[255];
}

__global__ void k_scan3(int* __restrict__ rowstart, const int* __restrict__ boff,
                        int N, int E) {
  int i = blockIdx.x * 256 + threadIdx.x;
  if (i < N) rowstart[i] += boff[blockIdx.x];
  if (i == 0) rowstart[N] = E;
}

__global__ void k_fill(const int* __restrict__ src, const int* __restrict__ dst,
                       const int* __restrict__ et, const int* __restrict__ rowstart,
                       int* __restrict__ cursor, int* __restrict__ packed, int E) {
  int e = blockIdx.x * 256 + threadIdx.x;
  if (e >= E) return;
  int n = dst[e];
  int pos = atomicAdd(&cursor[n], 1);
  packed[rowstart[n] + pos] = (src[e] << 3) | et[e];
}

// ---------------- small converts ----------------
__global__ void k_xcast(const float* __restrict__ x, __hip_bfloat16* __restrict__ xb, int n) {
  int i = blockIdx.x * 256 + threadIdx.x;
  if (i < n) xb[i] = __float2bfloat16(x[i]);
}

// Wb[nn][kk] (row-major [128][1152] bf16): kk<1024 -> W_w[kk/128][kk%128][nn], else W_res[kk-1024][nn]
__global__ void k_wb(const float* __restrict__ Ww, const float* __restrict__ Wres,
                     __hip_bfloat16* __restrict__ Wb) {
  int o = blockIdx.x * 256 + threadIdx.x;
  if (o >= 128 * KTOT) return;
  int nn = o / KTOT, kk = o % KTOT;
  float v = (kk < 1024) ? Ww[(kk >> 7) * 16384 + (kk & 127) * 128 + nn]
                        : Wres[(kk - 1024) * 128 + nn];
  Wb[o] = __float2bfloat16(v);
}

// ---------------- per-node typed aggregation ----------------
__global__ __launch_bounds__(128) void k_agg(
    const __hip_bfloat16* __restrict__ xb, const int* __restrict__ rowstart,
    const int* __restrict__ packed, __hip_bfloat16* __restrict__ agg) {
  const int n = blockIdx.x;
  const int f = threadIdx.x;  // 0..127, owns feature column f
  __shared__ float acc[8][128];
#pragma unroll
  for (int t = 0; t < 8; ++t) acc[t][f] = 0.f;
  // no barrier needed: thread f is the only reader/writer of column f

  int e = rowstart[n];
  const int end = rowstart[n + 1];
  for (; e + 1 < end; e += 2) {
    int p0 = packed[e], p1 = packed[e + 1];
    float v0 = __bfloat162float(xb[(long)(p0 >> 3) * 128 + f]);
    float v1 = __bfloat162float(xb[(long)(p1 >> 3) * 128 + f]);
    acc[p0 & 7][f] += v0;
    acc[p1 & 7][f] += v1;
  }
  if (e < end) {
    int p = packed[e];
    acc[p & 7][f] += __bfloat162float(xb[(long)(p >> 3) * 128 + f]);
  }

  const long base = (long)n * KTOT;
#pragma unroll
  for (int t = 0; t < 8; ++t) agg[base + t * 128 + f] = __float2bfloat16(acc[t][f]);
  agg[base + 1024 + f] = xb[(long)n * 128 + f];  // residual K-block
}

// ---------------- GEMM: [padM,1152] x [1152,128], bias + ELU ----------------
// A = agg (row-major, stride KTOT), Bt = Wb (row-major [128 n][1152 k]).
// 128x128 tile, BK=64, 4 waves (2x2), each wave 64x64 = 4x4 frags of 16x16x32 bf16.
// LDS XOR-swizzle st-style: byte ^= (row&7)<<4, applied on pre-swizzled global src
// (global_load_lds writes linearly) and on the ds_read side.
__global__ __launch_bounds__(256) void k_gemm(
    const __hip_bfloat16* __restrict__ agg, const __hip_bfloat16* __restrict__ Wb,
    const float* __restrict__ bres, float* __restrict__ out, int M) {
  constexpr int BK = 64;
  constexpr int NSTEP = KTOT / BK;  // 18
  __shared__ __align__(16) unsigned short As[128 * BK];
  __shared__ __align__(16) unsigned short Bs[128 * BK];

  const int tid = threadIdx.x;
  const int lane = tid & 63;
  const int wid = tid >> 6;
  const int wr = wid >> 1, wc = wid & 1;
  const int row0 = blockIdx.x * 128;

  f32x4 acc[4][4] = {};

  const int sr = tid >> 3;            // staging row within 32-row chunk
  const int scb = (tid & 7) << 4;     // staging col byte 0..112
  const char* aggb = (const char*)agg;
  const char* wbb = (const char*)Wb;
  char* asb = (char*)As;
  char* bsb = (char*)Bs;

  for (int kt = 0; kt < NSTEP; ++kt) {
    const long kb0 = (long)kt * (BK * 2);  // 128 bytes per K-step
#pragma unroll
    for (int j = 0; j < 4; ++j) {
      int r = j * 32 + sr;
      int srcb = scb ^ ((r & 7) << 4);  // pre-swizzled global source column
      gload_lds16(aggb + (long)(row0 + r) * (KTOT * 2) + kb0 + srcb,
                  asb + r * 128 + scb);
      gload_lds16(wbb + (long)r * (KTOT * 2) + kb0 + srcb,
                  bsb + r * 128 + scb);
    }
    asm volatile("s_waitcnt vmcnt(0)" ::: "memory");
    __syncthreads();

#pragma unroll
    for (int ks = 0; ks < 2; ++ks) {
      bf16x8 af[4], bfr[4];
      const int cb = ks * 64 + ((lane >> 4) << 4);  // K byte offset of this lane's 8 elems
#pragma unroll
      for (int mi = 0; mi < 4; ++mi) {
        int row = wr * 64 + mi * 16 + (lane & 15);
        af[mi] = *(const bf16x8*)(asb + ((row * 128 + cb) ^ ((row & 7) << 4)));
      }
#pragma unroll
      for (int ni = 0; ni < 4; ++ni) {
        int rowb = wc * 64 + ni * 16 + (lane & 15);
        bfr[ni] = *(const bf16x8*)(bsb + ((rowb * 128 + cb) ^ ((rowb & 7) << 4)));
      }
#pragma unroll
      for (int mi = 0; mi < 4; ++mi)
#pragma unroll
        for (int ni = 0; ni < 4; ++ni)
          acc[mi][ni] = __builtin_amdgcn_mfma_f32_16x16x32_bf16(
              af[mi], bfr[ni], acc[mi][ni], 0, 0, 0);
    }
    __syncthreads();
  }

  // epilogue: bias + ELU, C/D layout: col = lane&15, row = (lane>>4)*4 + q
#pragma unroll
  for (int mi = 0; mi < 4; ++mi) {
#pragma unroll
    for (int ni = 0; ni < 4; ++ni) {
      int col = wc * 64 + ni * 16 + (lane & 15);
      float bias = bres[col];
      int rb = row0 + wr * 64 + mi * 16 + ((lane >> 4) << 2);
      f32x4 v = acc[mi][ni];
#pragma unroll
      for (int q = 0; q < 4; ++q) {
        int row = rb + q;
        if (row < M) {
          float o = v[q] + bias;
          out[(long)row * 128 + col] = (o > 0.f) ? o : (expf(o) - 1.f);
        }
      }
    }
  }
}

extern "C" void kernel_launch(void* const* d_in, const int* in_sizes, int n_in,
                              void* d_out, int out_size, void* d_ws, size_t ws_size,
                              hipStream_t stream) {
  const float* x = (const float*)d_in[0];
  const int* src = (const int*)d_in[1];
  const int* dst = (const int*)d_in[2];
  const int* et = (const int*)d_in[3];
  const float* Ww = (const float*)d_in[4];
  // d_in[5] (W_al), d_in[6] (W_ar): dead in the reference output
  const float* Wres = (const float*)d_in[7];
  const float* bres = (const float*)d_in[8];
  float* out = (float*)d_out;

  const int N = in_sizes[0] / 128;
  const int E = in_sizes[1];
  const int padM = ((N + 127) / 128) * 128;

  char* ws = (char*)d_ws;
  size_t off = 0;
  auto take = [&](size_t b) {
    char* p = ws + off;
    off = (off + b + 255) & ~(size_t)255;
    return p;
  };
  __hip_bfloat16* agg = (__hip_bfloat16*)take((size_t)padM * KTOT * 2);
  __hip_bfloat16* Wb = (__hip_bfloat16*)take((size_t)128 * KTOT * 2);
  __hip_bfloat16* xb = (__hip_bfloat16*)take((size_t)N * 128 * 2);
  int* rowstart = (int*)take((size_t)(N + 1) * 4);
  int* deg = (int*)take((size_t)N * 4);
  int* cursor = (int*)take((size_t)N * 4);
  int* bsum = (int*)take(256 * 4);
  int* boff = (int*)take(256 * 4);
  int* packed = (int*)take((size_t)E * 4);

  hipMemsetAsync(deg, 0, (size_t)N * 4, stream);
  hipMemsetAsync(cursor, 0, (size_t)N * 4, stream);

  const int NB = (N + 255) / 256;  // 196 (<256, so one-level block-sum scan works)
  k_hist<<<(E + 255) / 256, 256, 0, stream>>>(dst, deg, E);
  k_scan<<<NB, 256, 0, stream>>>(deg, rowstart, bsum, N);
  k_scan<<<1, 256, 0, stream>>>(bsum, boff, nullptr, NB);
  k_scan3<<<NB, 256, 0, stream>>>(rowstart, boff, N, E);
  k_fill<<<(E + 255) / 256, 256, 0, stream>>>(src, dst, et, rowstart, cursor, packed, E);
  k_wb<<<(128 * KTOT + 255) / 256, 256, 0, stream>>>(Ww, Wres, Wb);
  k_xcast<<<(N * 128 + 255) / 256, 256, 0, stream>>>(x, xb, N * 128);
  k_agg<<<N, 128, 0, stream>>>(xb, rowstart, packed, agg);
  k_gemm<<<padM / 128, 256, 0, stream>>>(agg, Wb, bres, out, N);
}

// Round 2
// 282.941 us; speedup vs baseline: 1.0262x; 1.0262x over previous
//
#include <hip/hip_runtime.h>
#include <hip/hip_bf16.h>

// out = elu(segment_sum(typed_linear(x[src], W_w, etype), dst) + x@W_res + b_res)
// Attention path of the reference is dead code.
//
// Pipeline: CSR(dst) -> per-node typed aggregation agg[N, 8*128 (+128 residual)]
// bf16 -> one MFMA GEMM [padM,1152]x[1152,128] with bias+ELU epilogue.

#define KTOT 1152  // 8*128 typed agg + 128 x-residual

typedef __bf16 bf16x8 __attribute__((ext_vector_type(8)));
typedef float f32x4 __attribute__((ext_vector_type(4)));

__device__ __forceinline__ void gload_lds16(const void* g, void* l) {
  __builtin_amdgcn_global_load_lds(
      (const __attribute__((address_space(1))) unsigned int*)g,
      (__attribute__((address_space(3))) unsigned int*)l, 16, 0, 0);
}

// ---------------- CSR build ----------------
__global__ void k_hist(const int* __restrict__ dst, int* __restrict__ deg, int E) {
  int e = blockIdx.x * 256 + threadIdx.x;
  if (e < E) atomicAdd(&deg[dst[e]], 1);
}

__global__ void k_scan(const int* __restrict__ in, int* __restrict__ out_ex,
                       int* __restrict__ bsum, int N) {
  __shared__ int s[256];
  int tid = threadIdx.x;
  int i = blockIdx.x * 256 + tid;
  int v = (i < N) ? in[i] : 0;
  s[tid] = v;
  __syncthreads();
  for (int off = 1; off < 256; off <<= 1) {
    int t = (tid >= off) ? s[tid - off] : 0;
    __syncthreads();
    if (tid >= off) s[tid] += t;
    __syncthreads();
  }
  if (i < N) out_ex[i] = s[tid] - v;
  if (bsum != nullptr && tid == 255) bsum[blockIdx.x] = s[255];
}

__global__ void k_scan3(int* __restrict__ rowstart, const int* __restrict__ boff,
                        int N, int E) {
  int i = blockIdx.x * 256 + threadIdx.x;
  if (i < N) rowstart[i] += boff[blockIdx.x];
  if (i == 0) rowstart[N] = E;
}

__global__ void k_fill(const int* __restrict__ src, const int* __restrict__ dst,
                       const int* __restrict__ et, const int* __restrict__ rowstart,
                       int* __restrict__ cursor, int* __restrict__ packed, int E) {
  int e = blockIdx.x * 256 + threadIdx.x;
  if (e >= E) return;
  int n = dst[e];
  int pos = atomicAdd(&cursor[n], 1);
  packed[rowstart[n] + pos] = (src[e] << 3) | et[e];
}

// ---------------- small converts ----------------
__global__ void k_xcast(const float* __restrict__ x, __hip_bfloat16* __restrict__ xb, int n) {
  int i = blockIdx.x * 256 + threadIdx.x;
  if (i < n) xb[i] = __float2bfloat16(x[i]);
}

__global__ void k_wb(const float* __restrict__ Ww, const float* __restrict__ Wres,
                     __hip_bfloat16* __restrict__ Wb) {
  int o = blockIdx.x * 256 + threadIdx.x;
  if (o >= 128 * KTOT) return;
  int nn = o / KTOT, kk = o % KTOT;
  float v = (kk < 1024) ? Ww[(kk >> 7) * 16384 + (kk & 127) * 128 + nn]
                        : Wres[(kk - 1024) * 128 + nn];
  Wb[o] = __float2bfloat16(v);
}

// ---------------- per-node typed aggregation ----------------
// 1 wave per node; lane owns feature pair (2*lane, 2*lane+1); per-wave LDS acc.
// Chunk-8 prefetch: 8 independent gathers in flight before the 8 LDS RMWs.
__device__ __forceinline__ float2 fetch2(const ushort2* __restrict__ x2, int p, int lane) {
  ushort2 r = x2[(long)(p >> 3) * 64 + lane];
  return make_float2(__uint_as_float((unsigned)r.x << 16),
                     __uint_as_float((unsigned)r.y << 16));
}

__global__ __launch_bounds__(256) void k_agg(
    const __hip_bfloat16* __restrict__ xb, const int* __restrict__ rowstart,
    const int* __restrict__ packed, __hip_bfloat16* __restrict__ agg, int N) {
  __shared__ float2 accS[4][8][64];
  const int w = threadIdx.x >> 6, lane = threadIdx.x & 63;
  const int n = blockIdx.x * 4 + w;
  if (n >= N) return;  // no barriers anywhere: safe
#pragma unroll
  for (int t = 0; t < 8; ++t) accS[w][t][lane] = make_float2(0.f, 0.f);

  const ushort2* x2 = (const ushort2*)xb;
  int e = rowstart[n];
  const int end = rowstart[n + 1];

  for (; e + 8 <= end; e += 8) {
    int p[8];
    float2 v[8];
#pragma unroll
    for (int j = 0; j < 8; ++j) p[j] = packed[e + j];
#pragma unroll
    for (int j = 0; j < 8; ++j) v[j] = fetch2(x2, p[j], lane);
#pragma unroll
    for (int j = 0; j < 8; ++j) {
      float2 a = accS[w][p[j] & 7][lane];
      a.x += v[j].x;
      a.y += v[j].y;
      accS[w][p[j] & 7][lane] = a;
    }
  }
  for (; e + 2 <= end; e += 2) {
    int p0 = packed[e], p1 = packed[e + 1];
    float2 v0 = fetch2(x2, p0, lane), v1 = fetch2(x2, p1, lane);
    float2 a0 = accS[w][p0 & 7][lane];
    a0.x += v0.x; a0.y += v0.y;
    accS[w][p0 & 7][lane] = a0;
    float2 a1 = accS[w][p1 & 7][lane];
    a1.x += v1.x; a1.y += v1.y;
    accS[w][p1 & 7][lane] = a1;
  }
  if (e < end) {
    int p = packed[e];
    float2 v = fetch2(x2, p, lane);
    float2 a = accS[w][p & 7][lane];
    a.x += v.x; a.y += v.y;
    accS[w][p & 7][lane] = a;
  }

  const long base = (long)n * KTOT;
#pragma unroll
  for (int t = 0; t < 8; ++t) {
    float2 a = accS[w][t][lane];
    __hip_bfloat162 ob;
    ob.x = __float2bfloat16(a.x);
    ob.y = __float2bfloat16(a.y);
    *(__hip_bfloat162*)(agg + base + t * 128 + 2 * lane) = ob;
  }
  ((ushort2*)(agg + base + 1024))[lane] = x2[(long)n * 64 + lane];  // residual
}

// ---------------- GEMM: [padM,1152] x [1152,128], bias + ELU ----------------
// BM=64, BK=64, 256 threads (4 waves, wave w owns cols w*32..w*32+31).
// Double-buffered LDS, 2-phase pipeline (prefetch t+1 while computing t).
// XOR swizzle ^((row&7)<<4) applied on pre-swizzled global source + ds_read.
__global__ __launch_bounds__(256) void k_gemm(
    const __hip_bfloat16* __restrict__ agg, const __hip_bfloat16* __restrict__ Wb,
    const float* __restrict__ bres, float* __restrict__ out, int M) {
  constexpr int BK = 64;
  constexpr int NSTEP = KTOT / BK;  // 18
  __shared__ __align__(16) unsigned short As[2][64 * BK];
  __shared__ __align__(16) unsigned short Bs[2][128 * BK];

  const int tid = threadIdx.x;
  const int lane = tid & 63;
  const int w = tid >> 6;
  const int row0 = blockIdx.x * 64;

  f32x4 acc[4][2] = {};
  const char* aggb = (const char*)agg;
  const char* wbb = (const char*)Wb;

  auto stage = [&](int buf, int kt) {
    const long kb0 = (long)kt * (BK * 2);
    char* asb = (char*)As[buf];
    char* bsb = (char*)Bs[buf];
#pragma unroll
    for (int rnd = 0; rnd < 2; ++rnd) {
      int c = rnd * 256 + tid;
      int r = c >> 3, colb = (c & 7) << 4;
      int srcb = colb ^ ((r & 7) << 4);
      gload_lds16(aggb + (long)(row0 + r) * (KTOT * 2) + kb0 + srcb,
                  asb + r * 128 + colb);
    }
#pragma unroll
    for (int rnd = 0; rnd < 4; ++rnd) {
      int c = rnd * 256 + tid;
      int r = c >> 3, colb = (c & 7) << 4;
      int srcb = colb ^ ((r & 7) << 4);
      gload_lds16(wbb + (long)r * (KTOT * 2) + kb0 + srcb, bsb + r * 128 + colb);
    }
  };

  stage(0, 0);
  asm volatile("s_waitcnt vmcnt(0)" ::: "memory");
  __syncthreads();

  int cur = 0;
  for (int kt = 0; kt < NSTEP; ++kt) {
    if (kt + 1 < NSTEP) stage(cur ^ 1, kt + 1);
    const char* asb = (const char*)As[cur];
    const char* bsb = (const char*)Bs[cur];
#pragma unroll
    for (int ks = 0; ks < 2; ++ks) {
      const int cb = ks * 64 + ((lane >> 4) << 4);
      bf16x8 af[4], bfr[2];
#pragma unroll
      for (int mi = 0; mi < 4; ++mi) {
        int row = mi * 16 + (lane & 15);
        af[mi] = *(const bf16x8*)(asb + ((row * 128 + cb) ^ ((row & 7) << 4)));
      }
#pragma unroll
      for (int ni = 0; ni < 2; ++ni) {
        int rowb = w * 32 + ni * 16 + (lane & 15);
        bfr[ni] = *(const bf16x8*)(bsb + ((rowb * 128 + cb) ^ ((rowb & 7) << 4)));
      }
#pragma unroll
      for (int mi = 0; mi < 4; ++mi)
#pragma unroll
        for (int ni = 0; ni < 2; ++ni)
          acc[mi][ni] = __builtin_amdgcn_mfma_f32_16x16x32_bf16(
              af[mi], bfr[ni], acc[mi][ni], 0, 0, 0);
    }
    asm volatile("s_waitcnt vmcnt(0)" ::: "memory");
    __syncthreads();
    cur ^= 1;
  }

  // epilogue: C/D layout col=lane&15, row=(lane>>4)*4+q
#pragma unroll
  for (int mi = 0; mi < 4; ++mi) {
#pragma unroll
    for (int ni = 0; ni < 2; ++ni) {
      int col = w * 32 + ni * 16 + (lane & 15);
      float bias = bres[col];
      int rb = row0 + mi * 16 + ((lane >> 4) << 2);
      f32x4 v = acc[mi][ni];
#pragma unroll
      for (int q = 0; q < 4; ++q) {
        int row = rb + q;
        if (row < M) {
          float o = v[q] + bias;
          out[(long)row * 128 + col] = (o > 0.f) ? o : (expf(o) - 1.f);
        }
      }
    }
  }
}

extern "C" void kernel_launch(void* const* d_in, const int* in_sizes, int n_in,
                              void* d_out, int out_size, void* d_ws, size_t ws_size,
                              hipStream_t stream) {
  const float* x = (const float*)d_in[0];
  const int* src = (const int*)d_in[1];
  const int* dst = (const int*)d_in[2];
  const int* et = (const int*)d_in[3];
  const float* Ww = (const float*)d_in[4];
  const float* Wres = (const float*)d_in[7];
  const float* bres = (const float*)d_in[8];
  float* out = (float*)d_out;

  const int N = in_sizes[0] / 128;
  const int E = in_sizes[1];
  const int padM = ((N + 127) / 128) * 128;

  char* ws = (char*)d_ws;
  size_t off = 0;
  auto take = [&](size_t b) {
    char* p = ws + off;
    off = (off + b + 255) & ~(size_t)255;
    return p;
  };
  __hip_bfloat16* agg = (__hip_bfloat16*)take((size_t)padM * KTOT * 2);
  __hip_bfloat16* Wb = (__hip_bfloat16*)take((size_t)128 * KTOT * 2);
  __hip_bfloat16* xb = (__hip_bfloat16*)take((size_t)N * 128 * 2);
  int* rowstart = (int*)take((size_t)(N + 1) * 4);
  int* deg = (int*)take((size_t)N * 4);
  int* cursor = (int*)take((size_t)N * 4);
  int* bsum = (int*)take(256 * 4);
  int* boff = (int*)take(256 * 4);
  int* packed = (int*)take((size_t)E * 4);

  hipMemsetAsync(deg, 0, (size_t)N * 4, stream);
  hipMemsetAsync(cursor, 0, (size_t)N * 4, stream);

  const int NB = (N + 255) / 256;  // 196 < 256: one-level block-sum scan OK
  k_hist<<<(E + 255) / 256, 256, 0, stream>>>(dst, deg, E);
  k_scan<<<NB, 256, 0, stream>>>(deg, rowstart, bsum, N);
  k_scan<<<1, 256, 0, stream>>>(bsum, boff, nullptr, NB);
  k_scan3<<<NB, 256, 0, stream>>>(rowstart, boff, N, E);
  k_fill<<<(E + 255) / 256, 256, 0, stream>>>(src, dst, et, rowstart, cursor, packed, E);
  k_wb<<<(128 * KTOT + 255) / 256, 256, 0, stream>>>(Ww, Wres, Wb);
  k_xcast<<<(N * 128 + 255) / 256, 256, 0, stream>>>(x, xb, N * 128);
  k_agg<<<(N + 3) / 4, 256, 0, stream>>>(xb, rowstart, packed, agg, N);
  k_gemm<<<padM / 64, 256, 0, stream>>>(agg, Wb, bres, out, N);
}

// Round 3
// 264.400 us; speedup vs baseline: 1.0981x; 1.0701x over previous
//
#include <hip/hip_runtime.h>
#include <hip/hip_bf16.h>

// out = elu(segment_sum(typed_linear(x[src], W_w, etype), dst) + x@W_res + b_res)
// (attention path of the reference is dead code)
//
// Restructured: y = x @ [W_0..W_7, W_res]  ([N,128]x[128,1152] dense MFMA GEMM),
// then out[n] = elu(sum_{e: dst=n} y[src[e], et*128..] + y[n,1024..] + b_res).
// No fat intermediate round-trip through a second GEMM; scatter is pure
// register accumulation over coalesced 256B row slices of L3-resident y.

#define KW 1152  // 9*128 columns of y (8 types + residual)

typedef __bf16 bf16x8 __attribute__((ext_vector_type(8)));
typedef float f32x4 __attribute__((ext_vector_type(4)));

__device__ __forceinline__ void gload_lds16(const void* g, void* l) {
  __builtin_amdgcn_global_load_lds(
      (const __attribute__((address_space(1))) unsigned int*)g,
      (__attribute__((address_space(3))) unsigned int*)l, 16, 0, 0);
}

// ---------------- CSR build ----------------
__global__ void k_hist(const int* __restrict__ dst, int* __restrict__ deg, int E) {
  int e = blockIdx.x * 256 + threadIdx.x;
  if (e < E) atomicAdd(&deg[dst[e]], 1);
}

__global__ void k_scan(const int* __restrict__ in, int* __restrict__ out_ex,
                       int* __restrict__ bsum, int N) {
  __shared__ int s[256];
  int tid = threadIdx.x;
  int i = blockIdx.x * 256 + tid;
  int v = (i < N) ? in[i] : 0;
  s[tid] = v;
  __syncthreads();
  for (int off = 1; off < 256; off <<= 1) {
    int t = (tid >= off) ? s[tid - off] : 0;
    __syncthreads();
    if (tid >= off) s[tid] += t;
    __syncthreads();
  }
  if (i < N) out_ex[i] = s[tid] - v;
  if (bsum != nullptr && tid == 255) bsum[blockIdx.x] = s[255];
}

__global__ void k_scan3(int* __restrict__ rowstart, const int* __restrict__ boff,
                        int N, int E) {
  int i = blockIdx.x * 256 + threadIdx.x;
  if (i < N) rowstart[i] += boff[blockIdx.x];
  if (i == 0) rowstart[N] = E;
}

// packed[e] = src*576 + etype*64  (ushort2-unit offset of the y slice)
__global__ void k_fill(const int* __restrict__ src, const int* __restrict__ dst,
                       const int* __restrict__ et, const int* __restrict__ rowstart,
                       int* __restrict__ cursor, int* __restrict__ packed, int E) {
  int e = blockIdx.x * 256 + threadIdx.x;
  if (e >= E) return;
  int n = dst[e];
  int pos = atomicAdd(&cursor[n], 1);
  packed[rowstart[n] + pos] = src[e] * 576 + (et[e] << 6);
}

// ---------------- converts ----------------
__global__ void k_xcast(const float* __restrict__ x, __hip_bfloat16* __restrict__ xb,
                        int n, int npad) {
  int i = blockIdx.x * 256 + threadIdx.x;
  if (i < npad) xb[i] = __float2bfloat16(i < n ? x[i] : 0.f);
}

// Wb row-major [1152 n][128 k]: n<1024 -> W_w[n>>7][k][n&127], else W_res[k][n&127]
__global__ void k_wb(const float* __restrict__ Ww, const float* __restrict__ Wres,
                     __hip_bfloat16* __restrict__ Wb) {
  int o = blockIdx.x * 256 + threadIdx.x;
  if (o >= KW * 128) return;
  int nn = o >> 7, kk = o & 127;
  float v = (nn < 1024) ? Ww[(nn >> 7) * 16384 + kk * 128 + (nn & 127)]
                        : Wres[kk * 128 + (nn & 127)];
  Wb[o] = __float2bfloat16(v);
}

// ---------------- y GEMM: [padM,128] x [128,1152] -> y bf16 ----------------
// grid (padM/128, 9), 512 threads (8 waves, 2x4), single K=128 shot.
// XOR swizzle ^((row&7)<<4) via pre-swizzled global source + swizzled ds_read.
__global__ __launch_bounds__(512) void k_ygemm(
    const __hip_bfloat16* __restrict__ xb, const __hip_bfloat16* __restrict__ Wb,
    __hip_bfloat16* __restrict__ y) {
  __shared__ __align__(16) unsigned short As[128 * 128];
  __shared__ __align__(16) unsigned short Bs[128 * 128];
  const int tid = threadIdx.x;
  const int lane = tid & 63;
  const int wid = tid >> 6;
  const int wr = wid >> 2, wc = wid & 3;  // 2 x 4 waves -> 64x32 per wave
  const long row0 = (long)blockIdx.x * 128;
  const int nb0 = blockIdx.y * 128;

  const char* xbb = (const char*)xb;
  const char* wbb = (const char*)Wb;
  char* asb = (char*)As;
  char* bsb = (char*)Bs;

#pragma unroll
  for (int i = 0; i < 8; ++i) {
    int c = i * 512 + tid;
    int half = c >> 11;      // 0: A, 1: B
    int cc = c & 2047;
    int r = cc >> 4, colb = (cc & 15) << 4;
    int srcb = colb ^ ((r & 7) << 4);
    if (half == 0)
      gload_lds16(xbb + (row0 + r) * 256 + srcb, asb + r * 256 + colb);
    else
      gload_lds16(wbb + (long)(nb0 + r) * 256 + srcb, bsb + r * 256 + colb);
  }
  asm volatile("s_waitcnt vmcnt(0)" ::: "memory");
  __syncthreads();

  f32x4 acc[4][2] = {};
#pragma unroll
  for (int ks = 0; ks < 4; ++ks) {
    const int cb = ks * 64 + ((lane >> 4) << 4);
    bf16x8 af[4], bfr[2];
#pragma unroll
    for (int mi = 0; mi < 4; ++mi) {
      int row = wr * 64 + mi * 16 + (lane & 15);
      af[mi] = *(const bf16x8*)(asb + ((row * 256 + cb) ^ ((row & 7) << 4)));
    }
#pragma unroll
    for (int ni = 0; ni < 2; ++ni) {
      int rowb = wc * 32 + ni * 16 + (lane & 15);
      bfr[ni] = *(const bf16x8*)(bsb + ((rowb * 256 + cb) ^ ((rowb & 7) << 4)));
    }
#pragma unroll
    for (int mi = 0; mi < 4; ++mi)
#pragma unroll
      for (int ni = 0; ni < 2; ++ni)
        acc[mi][ni] = __builtin_amdgcn_mfma_f32_16x16x32_bf16(
            af[mi], bfr[ni], acc[mi][ni], 0, 0, 0);
  }

  // C/D layout: col = lane&15, row = (lane>>4)*4 + q
#pragma unroll
  for (int mi = 0; mi < 4; ++mi)
#pragma unroll
    for (int ni = 0; ni < 2; ++ni) {
      int col = nb0 + wc * 32 + ni * 16 + (lane & 15);
      long rb = row0 + wr * 64 + mi * 16 + ((lane >> 4) << 2);
      f32x4 v = acc[mi][ni];
#pragma unroll
      for (int q = 0; q < 4; ++q)
        y[(rb + q) * KW + col] = __float2bfloat16(v[q]);
    }
}

// ---------------- scatter-sum + residual + bias + ELU ----------------
// 1 wave per node, lane owns cols (2*lane, 2*lane+1); f32x2 register acc;
// chunk-8 prefetch of coalesced 256B y-row slices.
__global__ __launch_bounds__(256) void k_scat(
    const ushort2* __restrict__ y2, const int* __restrict__ rowstart,
    const int* __restrict__ packed, const float* __restrict__ bres,
    float* __restrict__ out, int N) {
  const int w = threadIdx.x >> 6, lane = threadIdx.x & 63;
  const int n = blockIdx.x * 4 + w;
  if (n >= N) return;
  float ax = 0.f, ay = 0.f;
  int e = rowstart[n];
  const int end = rowstart[n + 1];
  for (; e + 8 <= end; e += 8) {
    int p[8];
#pragma unroll
    for (int j = 0; j < 8; ++j) p[j] = packed[e + j];
    ushort2 r[8];
#pragma unroll
    for (int j = 0; j < 8; ++j) r[j] = y2[p[j] + lane];
#pragma unroll
    for (int j = 0; j < 8; ++j) {
      ax += __uint_as_float((unsigned)r[j].x << 16);
      ay += __uint_as_float((unsigned)r[j].y << 16);
    }
  }
  for (; e < end; ++e) {
    ushort2 r = y2[packed[e] + lane];
    ax += __uint_as_float((unsigned)r.x << 16);
    ay += __uint_as_float((unsigned)r.y << 16);
  }
  ushort2 rr = y2[n * 576 + 512 + lane];  // residual slice y[n, 1024..]
  ax += __uint_as_float((unsigned)rr.x << 16) + bres[2 * lane];
  ay += __uint_as_float((unsigned)rr.y << 16) + bres[2 * lane + 1];
  float2 o;
  o.x = ax > 0.f ? ax : (expf(ax) - 1.f);
  o.y = ay > 0.f ? ay : (expf(ay) - 1.f);
  *(float2*)(out + (long)n * 128 + 2 * lane) = o;
}

extern "C" void kernel_launch(void* const* d_in, const int* in_sizes, int n_in,
                              void* d_out, int out_size, void* d_ws, size_t ws_size,
                              hipStream_t stream) {
  const float* x = (const float*)d_in[0];
  const int* src = (const int*)d_in[1];
  const int* dst = (const int*)d_in[2];
  const int* et = (const int*)d_in[3];
  const float* Ww = (const float*)d_in[4];
  const float* Wres = (const float*)d_in[7];
  const float* bres = (const float*)d_in[8];
  float* out = (float*)d_out;

  const int N = in_sizes[0] / 128;
  const int E = in_sizes[1];
  const int padM = ((N + 127) / 128) * 128;

  char* ws = (char*)d_ws;
  size_t off = 0;
  auto take = [&](size_t b) {
    char* p = ws + off;
    off = (off + b + 255) & ~(size_t)255;
    return p;
  };
  __hip_bfloat16* y = (__hip_bfloat16*)take((size_t)padM * KW * 2);
  __hip_bfloat16* Wb = (__hip_bfloat16*)take((size_t)KW * 128 * 2);
  __hip_bfloat16* xb = (__hip_bfloat16*)take((size_t)padM * 128 * 2);
  int* rowstart = (int*)take((size_t)(N + 1) * 4);
  int* deg = (int*)take((size_t)N * 4);
  int* cursor = (int*)take((size_t)N * 4);
  int* bsum = (int*)take(256 * 4);
  int* boff = (int*)take(256 * 4);
  int* packed = (int*)take((size_t)E * 4);

  hipMemsetAsync(deg, 0, (size_t)N * 4, stream);
  hipMemsetAsync(cursor, 0, (size_t)N * 4, stream);

  const int NB = (N + 255) / 256;  // < 256: one-level block-sum scan OK
  k_hist<<<(E + 255) / 256, 256, 0, stream>>>(dst, deg, E);
  k_scan<<<NB, 256, 0, stream>>>(deg, rowstart, bsum, N);
  k_scan<<<1, 256, 0, stream>>>(bsum, boff, nullptr, NB);
  k_scan3<<<NB, 256, 0, stream>>>(rowstart, boff, N, E);
  k_fill<<<(E + 255) / 256, 256, 0, stream>>>(src, dst, et, rowstart, cursor, packed, E);
  k_wb<<<(KW * 128 + 255) / 256, 256, 0, stream>>>(Ww, Wres, Wb);
  k_xcast<<<(padM * 128 + 255) / 256, 256, 0, stream>>>(x, xb, N * 128, padM * 128);
  dim3 gy(padM / 128, 9);
  k_ygemm<<<gy, 512, 0, stream>>>(xb, Wb, y);
  k_scat<<<(N + 3) / 4, 256, 0, stream>>>((const ushort2*)y, rowstart, packed, bres, out, N);
}

// Round 4
// 207.688 us; speedup vs baseline: 1.3980x; 1.2731x over previous
//
#include <hip/hip_runtime.h>
#include <hip/hip_bf16.h>

// out = elu(segment_sum(typed_linear(x[src], W_w, etype), dst) + x@W_res + b_res)
// (attention path of the reference is dead code)
//
// y = x @ [W_0..W_7, W_res]  ([N,128]x[128,1152] dense MFMA GEMM), then
// out[n] = elu(sum_{e: dst=n} y[src[e], et*128..] + y[n,1024..] + b_res).
// CSR over dst built with a two-pass LDS counting sort (no random global
// atomics, coalesced scatter writes).

#define KW 1152    // 9*128 columns of y (8 types + residual)
#define CAP 6144   // per-coarse-bucket capacity (mean ~4081, +32 sigma)
#define CHUNK 4096 // edges per binning block

typedef __bf16 bf16x8 __attribute__((ext_vector_type(8)));
typedef float f32x4 __attribute__((ext_vector_type(4)));

__device__ __forceinline__ void gload_lds16(const void* g, void* l) {
  __builtin_amdgcn_global_load_lds(
      (const __attribute__((address_space(1))) unsigned int*)g,
      (__attribute__((address_space(3))) unsigned int*)l, 16, 0, 0);
}

// ---------------- CSR build: pass A — coarse binning by dst>>8 ----------------
// pack27 = (src<<11) | (et<<8) | (dst&255)   (requires N <= 65536, T <= 8)
__global__ __launch_bounds__(256) void k_binA(
    const int* __restrict__ src, const int* __restrict__ dst,
    const int* __restrict__ et, int* __restrict__ gCount,
    int* __restrict__ bucketBuf, int E) {
  __shared__ int buf[CHUNK];
  __shared__ unsigned char bkt[CHUNK];
  __shared__ int hist[256], sc[256], ls[256], cur[256], gb[256];
  const int tid = threadIdx.x;
  const int base = blockIdx.x * CHUNK;
  const int cnt = min(CHUNK, E - base);

  hist[tid] = 0;
  __syncthreads();
  for (int j = tid; j < cnt; j += 256) atomicAdd(&hist[dst[base + j] >> 8], 1);
  __syncthreads();
  sc[tid] = hist[tid];
  __syncthreads();
  for (int off = 1; off < 256; off <<= 1) {
    int t = (tid >= off) ? sc[tid - off] : 0;
    __syncthreads();
    if (tid >= off) sc[tid] += t;
    __syncthreads();
  }
  ls[tid] = sc[tid] - hist[tid];
  cur[tid] = ls[tid];
  gb[tid] = (hist[tid] > 0) ? atomicAdd(&gCount[tid], hist[tid]) : 0;
  __syncthreads();
  for (int j = tid; j < cnt; j += 256) {
    int e = base + j;
    int d = dst[e];
    int b = d >> 8;
    int pos = atomicAdd(&cur[b], 1);
    buf[pos] = (src[e] << 11) | (et[e] << 8) | (d & 255);
    bkt[pos] = (unsigned char)b;
  }
  __syncthreads();
  // grouped-by-bucket LDS order -> run-wise coalesced global writes
  for (int j = tid; j < cnt; j += 256) {
    int b = bkt[j];
    bucketBuf[b * CAP + gb[b] + (j - ls[b])] = buf[j];
  }
}

// exclusive scan of 256 coarse counts -> coarseBase; also rowstart[N]=E
__global__ __launch_bounds__(256) void k_scanC(
    const int* __restrict__ gCount, int* __restrict__ coarseBase,
    int* __restrict__ rowstart, int N, int E) {
  __shared__ int sc[256], h[256];
  int tid = threadIdx.x;
  h[tid] = gCount[tid];
  sc[tid] = h[tid];
  __syncthreads();
  for (int off = 1; off < 256; off <<= 1) {
    int t = (tid >= off) ? sc[tid - off] : 0;
    __syncthreads();
    if (tid >= off) sc[tid] += t;
    __syncthreads();
  }
  coarseBase[tid] = sc[tid] - h[tid];
  if (tid == 0) rowstart[N] = E;
}

// ---------------- CSR build: pass B — fine sort by dst&255 in LDS ----------------
__global__ __launch_bounds__(256) void k_sortB(
    const int* __restrict__ bucketBuf, const int* __restrict__ gCount,
    const int* __restrict__ coarseBase, int* __restrict__ rowstart,
    int* __restrict__ packed, int N) {
  __shared__ int raw[CAP];
  __shared__ int srt[CAP];
  __shared__ int hist[256], sc[256], bs[256], cur[256];
  const int b = blockIdx.x;
  const int tid = threadIdx.x;
  const int cnt = min(gCount[b], CAP);
  const int base = coarseBase[b];

  hist[tid] = 0;
  __syncthreads();
  for (int j = tid; j < cnt; j += 256) {
    int p = bucketBuf[b * CAP + j];
    raw[j] = p;
    atomicAdd(&hist[p & 255], 1);
  }
  __syncthreads();
  sc[tid] = hist[tid];
  __syncthreads();
  for (int off = 1; off < 256; off <<= 1) {
    int t = (tid >= off) ? sc[tid - off] : 0;
    __syncthreads();
    if (tid >= off) sc[tid] += t;
    __syncthreads();
  }
  bs[tid] = sc[tid] - hist[tid];
  cur[tid] = bs[tid];
  int node = b * 256 + tid;
  if (node < N) rowstart[node] = base + bs[tid];
  __syncthreads();
  for (int j = tid; j < cnt; j += 256) {
    int p = raw[j];
    int pos = atomicAdd(&cur[p & 255], 1);
    srt[pos] = p;
  }
  __syncthreads();
  // packed[e] = src*576 + et*64 (ushort2-unit offset of the y slice)
  for (int j = tid; j < cnt; j += 256) {
    int p = srt[j];
    packed[base + j] = (p >> 11) * 576 + (((p >> 8) & 7) << 6);
  }
}

// ---------------- converts ----------------
__global__ void k_xcast(const float* __restrict__ x, __hip_bfloat16* __restrict__ xb,
                        int n, int npad) {
  int i = blockIdx.x * 256 + threadIdx.x;
  if (i < npad) xb[i] = __float2bfloat16(i < n ? x[i] : 0.f);
}

// Wb row-major [1152 n][128 k]: n<1024 -> W_w[n>>7][k][n&127], else W_res[k][n&127]
__global__ void k_wb(const float* __restrict__ Ww, const float* __restrict__ Wres,
                     __hip_bfloat16* __restrict__ Wb) {
  int o = blockIdx.x * 256 + threadIdx.x;
  if (o >= KW * 128) return;
  int nn = o >> 7, kk = o & 127;
  float v = (nn < 1024) ? Ww[(nn >> 7) * 16384 + kk * 128 + (nn & 127)]
                        : Wres[kk * 128 + (nn & 127)];
  Wb[o] = __float2bfloat16(v);
}

// ---------------- y GEMM: [padM,128] x [128,1152] -> y bf16 ----------------
// grid (padM/128, 9), 512 threads (8 waves, 2x4), single K=128 shot.
// XOR swizzle ^((row&7)<<4) via pre-swizzled global source + swizzled ds_read.
__global__ __launch_bounds__(512) void k_ygemm(
    const __hip_bfloat16* __restrict__ xb, const __hip_bfloat16* __restrict__ Wb,
    __hip_bfloat16* __restrict__ y) {
  __shared__ __align__(16) unsigned short As[128 * 128];
  __shared__ __align__(16) unsigned short Bs[128 * 128];
  const int tid = threadIdx.x;
  const int lane = tid & 63;
  const int wid = tid >> 6;
  const int wr = wid >> 2, wc = wid & 3;  // 2 x 4 waves -> 64x32 per wave
  const long row0 = (long)blockIdx.x * 128;
  const int nb0 = blockIdx.y * 128;

  const char* xbb = (const char*)xb;
  const char* wbb = (const char*)Wb;
  char* asb = (char*)As;
  char* bsb = (char*)Bs;

#pragma unroll
  for (int i = 0; i < 8; ++i) {
    int c = i * 512 + tid;
    int half = c >> 11;  // 0: A, 1: B
    int cc = c & 2047;
    int r = cc >> 4, colb = (cc & 15) << 4;
    int srcb = colb ^ ((r & 7) << 4);
    if (half == 0)
      gload_lds16(xbb + (row0 + r) * 256 + srcb, asb + r * 256 + colb);
    else
      gload_lds16(wbb + (long)(nb0 + r) * 256 + srcb, bsb + r * 256 + colb);
  }
  asm volatile("s_waitcnt vmcnt(0)" ::: "memory");
  __syncthreads();

  f32x4 acc[4][2] = {};
#pragma unroll
  for (int ks = 0; ks < 4; ++ks) {
    const int cb = ks * 64 + ((lane >> 4) << 4);
    bf16x8 af[4], bfr[2];
#pragma unroll
    for (int mi = 0; mi < 4; ++mi) {
      int row = wr * 64 + mi * 16 + (lane & 15);
      af[mi] = *(const bf16x8*)(asb + ((row * 256 + cb) ^ ((row & 7) << 4)));
    }
#pragma unroll
    for (int ni = 0; ni < 2; ++ni) {
      int rowb = wc * 32 + ni * 16 + (lane & 15);
      bfr[ni] = *(const bf16x8*)(bsb + ((rowb * 256 + cb) ^ ((rowb & 7) << 4)));
    }
#pragma unroll
    for (int mi = 0; mi < 4; ++mi)
#pragma unroll
      for (int ni = 0; ni < 2; ++ni)
        acc[mi][ni] = __builtin_amdgcn_mfma_f32_16x16x32_bf16(
            af[mi], bfr[ni], acc[mi][ni], 0, 0, 0);
  }

  // C/D layout: col = lane&15, row = (lane>>4)*4 + q
#pragma unroll
  for (int mi = 0; mi < 4; ++mi)
#pragma unroll
    for (int ni = 0; ni < 2; ++ni) {
      int col = nb0 + wc * 32 + ni * 16 + (lane & 15);
      long rb = row0 + wr * 64 + mi * 16 + ((lane >> 4) << 2);
      f32x4 v = acc[mi][ni];
#pragma unroll
      for (int q = 0; q < 4; ++q)
        y[(rb + q) * KW + col] = __float2bfloat16(v[q]);
    }
}

// ---------------- scatter-sum + residual + bias + ELU ----------------
// 1 wave per node, lane owns cols (2*lane, 2*lane+1); f32 register acc;
// chunk-16 prefetch of coalesced 256B y-row slices (edge ptrs wave-uniform).
__global__ __launch_bounds__(256) void k_scat(
    const ushort2* __restrict__ y2, const int* __restrict__ rowstart,
    const int* __restrict__ packed, const float* __restrict__ bres,
    float* __restrict__ out, int N) {
  const int w = threadIdx.x >> 6, lane = threadIdx.x & 63;
  const int n = blockIdx.x * 4 + w;
  if (n >= N) return;
  float ax = 0.f, ay = 0.f;
  int e = rowstart[n];
  const int end = rowstart[n + 1];
  for (; e + 16 <= end; e += 16) {
    int p[16];
#pragma unroll
    for (int j = 0; j < 16; ++j) p[j] = packed[e + j];
    ushort2 r[16];
#pragma unroll
    for (int j = 0; j < 16; ++j) r[j] = y2[p[j] + lane];
#pragma unroll
    for (int j = 0; j < 16; ++j) {
      ax += __uint_as_float((unsigned)r[j].x << 16);
      ay += __uint_as_float((unsigned)r[j].y << 16);
    }
  }
  for (; e + 4 <= end; e += 4) {
    int p[4];
#pragma unroll
    for (int j = 0; j < 4; ++j) p[j] = packed[e + j];
    ushort2 r[4];
#pragma unroll
    for (int j = 0; j < 4; ++j) r[j] = y2[p[j] + lane];
#pragma unroll
    for (int j = 0; j < 4; ++j) {
      ax += __uint_as_float((unsigned)r[j].x << 16);
      ay += __uint_as_float((unsigned)r[j].y << 16);
    }
  }
  for (; e < end; ++e) {
    ushort2 r = y2[packed[e] + lane];
    ax += __uint_as_float((unsigned)r.x << 16);
    ay += __uint_as_float((unsigned)r.y << 16);
  }
  ushort2 rr = y2[n * 576 + 512 + lane];  // residual slice y[n, 1024..]
  ax += __uint_as_float((unsigned)rr.x << 16) + bres[2 * lane];
  ay += __uint_as_float((unsigned)rr.y << 16) + bres[2 * lane + 1];
  float2 o;
  o.x = ax > 0.f ? ax : (expf(ax) - 1.f);
  o.y = ay > 0.f ? ay : (expf(ay) - 1.f);
  *(float2*)(out + (long)n * 128 + 2 * lane) = o;
}

extern "C" void kernel_launch(void* const* d_in, const int* in_sizes, int n_in,
                              void* d_out, int out_size, void* d_ws, size_t ws_size,
                              hipStream_t stream) {
  const float* x = (const float*)d_in[0];
  const int* src = (const int*)d_in[1];
  const int* dst = (const int*)d_in[2];
  const int* et = (const int*)d_in[3];
  const float* Ww = (const float*)d_in[4];
  const float* Wres = (const float*)d_in[7];
  const float* bres = (const float*)d_in[8];
  float* out = (float*)d_out;

  const int N = in_sizes[0] / 128;  // 50000 (<= 65536 required by pack27)
  const int E = in_sizes[1];
  const int padM = ((N + 127) / 128) * 128;
  const int COARSE = (N + 255) >> 8;  // 196

  char* ws = (char*)d_ws;
  size_t off = 0;
  auto take = [&](size_t b) {
    char* p = ws + off;
    off = (off + b + 255) & ~(size_t)255;
    return p;
  };
  __hip_bfloat16* y = (__hip_bfloat16*)take((size_t)padM * KW * 2);
  __hip_bfloat16* Wb = (__hip_bfloat16*)take((size_t)KW * 128 * 2);
  __hip_bfloat16* xb = (__hip_bfloat16*)take((size_t)padM * 128 * 2);
  int* rowstart = (int*)take((size_t)(N + 1) * 4);
  int* gCount = (int*)take(256 * 4);
  int* coarseBase = (int*)take(256 * 4);
  int* packed = (int*)take((size_t)E * 4);
  // bucketBuf aliases y: consumed by k_sortB before k_ygemm writes y
  int* bucketBuf = (int*)y;  // COARSE*CAP*4 = 4.8 MB << y's 115 MB

  hipMemsetAsync(gCount, 0, 256 * 4, stream);
  k_binA<<<(E + CHUNK - 1) / CHUNK, 256, 0, stream>>>(src, dst, et, gCount, bucketBuf, E);
  k_scanC<<<1, 256, 0, stream>>>(gCount, coarseBase, rowstart, N, E);
  k_sortB<<<COARSE, 256, 0, stream>>>(bucketBuf, gCount, coarseBase, rowstart, packed, N);
  k_wb<<<(KW * 128 + 255) / 256, 256, 0, stream>>>(Ww, Wres, Wb);
  k_xcast<<<(padM * 128 + 255) / 256, 256, 0, stream>>>(x, xb, N * 128, padM * 128);
  dim3 gy(padM / 128, 9);
  k_ygemm<<<gy, 512, 0, stream>>>(xb, Wb, y);
  k_scat<<<(N + 3) / 4, 256, 0, stream>>>((const ushort2*)y, rowstart, packed, bres, out, N);
}